// Round 4
// baseline (8145.296 us; speedup 1.0000x reference)
//
#include <hip/hip_runtime.h>
#include <hip/hip_bf16.h>

typedef __hip_bfloat16 bf16;

#define D_MODEL 2048
#define SEQ     2048
#define NH      16
#define DH      128
#define BATCH   2
#define MTOT    (BATCH*SEQ)   // 4096

__device__ __forceinline__ float toF(bf16 x) { return __bfloat162float(x); }

// mode-dispatched I/O: f32flag=1 -> buffer is float32, else bfloat16
__device__ __forceinline__ float ldIO(const void* p, long i, int f32flag) {
    return f32flag ? ((const float*)p)[i] : toF(((const bf16*)p)[i]);
}
__device__ __forceinline__ void stIO(void* p, long i, float v, int f32flag) {
    if (f32flag) ((float*)p)[i] = v;
    else         ((bf16*)p)[i] = __float2bfloat16(v);
}

// ---------------------------------------------------------------------------
// dtype detector: scan X's first 16384 halfwords as bf16; count all-ones
// exponent patterns. True bf16 N(0,1) data: 0 hits. f32 data: the low
// halfword of each float is uniform-random -> ~32 hits expected.
// ---------------------------------------------------------------------------
__global__ void detect_k(const unsigned short* __restrict__ X, int* __restrict__ flag) {
    __shared__ int cnt;
    if (threadIdx.x == 0) cnt = 0;
    __syncthreads();
    int c = 0;
    for (int i = threadIdx.x; i < 16384; i += 256) {
        const unsigned short u = X[i];
        if (((u >> 7) & 0xFF) == 0xFF) ++c;   // bf16 exp field all ones (NaN/Inf)
    }
    atomicAdd(&cnt, c);
    __syncthreads();
    if (threadIdx.x == 0) flag[0] = (cnt >= 4) ? 1 : 0;   // 1 = float32 I/O
}

// ---------------------------------------------------------------------------
// Naive tiled GEMM: C[M, *] = A[M,Kdim] * B[Kdim,*] + bias
//   B z-indexed: Bz = B + z*bstride (elements). 64x64 tile, BK=16, f32 accum.
//   a_io/c_io: whether A/C are I/O buffers (dtype per flag) or internal bf16.
//   B and bias are always I/O buffers (weights).
// ---------------------------------------------------------------------------
__global__ __launch_bounds__(256) void gemm_naive_k(
    const void* __restrict__ A, int a_io,
    const void* __restrict__ B, const void* __restrict__ bias,
    void* __restrict__ C, int c_io,
    int Kdim, int ldb, int ldc, long bstride, int colstride, int biasstride,
    const int* __restrict__ flag)
{
    __shared__ float As[64][17];
    __shared__ float Bs[16][65];
    const int f32 = flag[0];
    const int aF = a_io ? f32 : 0;
    const int cF = c_io ? f32 : 0;

    const int z  = blockIdx.z;
    const long boff = (long)z * bstride;
    const int m0 = blockIdx.x * 64;
    const int n0 = blockIdx.y * 64;
    const int tid = threadIdx.x;
    const int ty = tid >> 4, tx = tid & 15;

    float acc[4][4];
#pragma unroll
    for (int i = 0; i < 4; ++i)
#pragma unroll
        for (int j = 0; j < 4; ++j) acc[i][j] = 0.f;

    for (int kb = 0; kb < Kdim; kb += 16) {
#pragma unroll
        for (int i = 0; i < 4; ++i) {
            const int idx = tid + i * 256;
            const int r = idx >> 4, c = idx & 15;
            As[r][c] = ldIO(A, (long)(m0 + r) * Kdim + kb + c, aF);
        }
#pragma unroll
        for (int i = 0; i < 4; ++i) {
            const int idx = tid + i * 256;
            const int r = idx >> 6, c = idx & 63;
            Bs[r][c] = ldIO(B, boff + (long)(kb + r) * ldb + n0 + c, f32);
        }
        __syncthreads();
#pragma unroll
        for (int k = 0; k < 16; ++k) {
            float a[4], b[4];
#pragma unroll
            for (int i = 0; i < 4; ++i) a[i] = As[ty * 4 + i][k];
#pragma unroll
            for (int j = 0; j < 4; ++j) b[j] = Bs[k][tx * 4 + j];
#pragma unroll
            for (int i = 0; i < 4; ++i)
#pragma unroll
                for (int j = 0; j < 4; ++j) acc[i][j] += a[i] * b[j];
        }
        __syncthreads();
    }

#pragma unroll
    for (int j = 0; j < 4; ++j) {
        const int ncol = n0 + tx * 4 + j;
        const float bv = ldIO(bias, z * biasstride + ncol, f32);
        const int ccol = z * colstride + ncol;
#pragma unroll
        for (int i = 0; i < 4; ++i) {
            const int row = m0 + ty * 4 + i;
            stIO(C, (long)row * ldc + ccol, acc[i][j] + bv, cF);
        }
    }
}

// ---------------------------------------------------------------------------
// Naive causal attention, one block per (q, b, h). Internal bf16 Q/K/V/Z.
// ---------------------------------------------------------------------------
__global__ __launch_bounds__(256) void attn_naive_k(
    const bf16* __restrict__ Q, const bf16* __restrict__ K,
    const bf16* __restrict__ V, bf16* __restrict__ Z)
{
    __shared__ float Qs[DH];
    __shared__ float P[SEQ];
    __shared__ float red[256];

    const int q  = blockIdx.x;
    const int bh = blockIdx.y;
    const int b = bh >> 4, h = bh & 15;
    const long base = (long)b * SEQ * D_MODEL + h * DH;
    const int tid = threadIdx.x;
    const float scale = 0.08838834764831845f;  // 1/sqrt(128)

    if (tid < DH) Qs[tid] = toF(Q[base + (long)q * D_MODEL + tid]);
    __syncthreads();

    float lmax = -1e30f;
    for (int k = tid; k <= q; k += 256) {
        const bf16* Kr = K + base + (long)k * D_MODEL;
        float s = 0.f;
#pragma unroll 8
        for (int d = 0; d < DH; ++d) s += Qs[d] * toF(Kr[d]);
        s *= scale;
        P[k] = s;
        lmax = fmaxf(lmax, s);
    }
    red[tid] = lmax;
    __syncthreads();
    for (int st = 128; st > 0; st >>= 1) {
        if (tid < st) red[tid] = fmaxf(red[tid], red[tid + st]);
        __syncthreads();
    }
    const float mx = red[0];
    __syncthreads();

    float lsum = 0.f;
    for (int k = tid; k <= q; k += 256) {
        const float p = __expf(P[k] - mx);
        P[k] = p;
        lsum += p;
    }
    red[tid] = lsum;
    __syncthreads();
    for (int st = 128; st > 0; st >>= 1) {
        if (tid < st) red[tid] += red[tid + st];
        __syncthreads();
    }
    const float inv = 1.f / red[0];

    if (tid < DH) {
        float acc = 0.f;
        for (int k = 0; k <= q; ++k)
            acc += P[k] * toF(V[base + (long)k * D_MODEL + tid]);
        Z[base + (long)q * D_MODEL + tid] = __float2bfloat16(acc * inv);
    }
}

extern "C" void kernel_launch(void* const* d_in, const int* in_sizes, int n_in,
                              void* d_out, int out_size, void* d_ws, size_t ws_size,
                              hipStream_t stream) {
    const void* X  = d_in[0];
    const void* WQ = d_in[1];   // [NH][D_MODEL][DH]
    const void* WK = d_in[2];
    const void* WV = d_in[3];
    const void* WO = d_in[4];   // [NH][DH][D_MODEL] == flat [D_MODEL][D_MODEL]
    const void* bQ = d_in[5];   // [NH][DH]
    const void* bK = d_in[6];
    const void* bV = d_in[7];
    const void* bO = d_in[8];   // [D_MODEL]

    bf16* ws = (bf16*)d_ws;
    const long MSZ = (long)MTOT * D_MODEL;   // 8,388,608 elems (16 MiB as bf16)
    bf16* Qb = ws;
    bf16* Kb = Qb + MSZ;
    bf16* Vb = Kb + MSZ;
    bf16* Zb = Vb + MSZ;
    int* flag = (int*)(Zb + MSZ);
    // ws use: 64 MiB + 4 B

    detect_k<<<1, 256, 0, stream>>>((const unsigned short*)X, flag);

    const long wstride = (long)D_MODEL * DH;
    gemm_naive_k<<<dim3(MTOT/64, DH/64, NH), 256, 0, stream>>>(
        X, 1, WQ, bQ, Qb, 0, D_MODEL, DH, D_MODEL, wstride, DH, DH, flag);
    gemm_naive_k<<<dim3(MTOT/64, DH/64, NH), 256, 0, stream>>>(
        X, 1, WK, bK, Kb, 0, D_MODEL, DH, D_MODEL, wstride, DH, DH, flag);
    gemm_naive_k<<<dim3(MTOT/64, DH/64, NH), 256, 0, stream>>>(
        X, 1, WV, bV, Vb, 0, D_MODEL, DH, D_MODEL, wstride, DH, DH, flag);

    attn_naive_k<<<dim3(SEQ, BATCH*NH), 256, 0, stream>>>(Qb, Kb, Vb, Zb);

    gemm_naive_k<<<dim3(MTOT/64, D_MODEL/64, 1), 256, 0, stream>>>(
        Zb, 0, WO, bO, d_out, 1, D_MODEL, D_MODEL, D_MODEL, 0, 0, 0, flag);
}

// Round 5
// 541.722 us; speedup vs baseline: 15.0359x; 15.0359x over previous
//
#include <hip/hip_runtime.h>
#include <hip/hip_bf16.h>

typedef __hip_bfloat16 bf16;
typedef __attribute__((ext_vector_type(8))) short bf16x8;  // 8 bf16 = 4 VGPRs (MFMA A/B frag)
typedef __attribute__((ext_vector_type(4))) float f32x4;   // MFMA C/D frag

#define D_MODEL 2048
#define SEQ     2048
#define NH      16
#define DH      128
#define BATCH   2
#define MTOT    (BATCH*SEQ)   // 4096

__device__ __forceinline__ void async_cp16(const bf16* g, bf16* l) {
    // wave-uniform LDS base; HW scatters lane i at base + i*16B
    __builtin_amdgcn_global_load_lds(
        (const __attribute__((address_space(1))) void*)g,
        (__attribute__((address_space(3))) void*)l, 16, 0, 0);
}

// ---------------- f32 -> bf16 elementwise convert (8 elems/thread) ----------------
__global__ __launch_bounds__(256) void cvt_k(const float* __restrict__ in,
                                             bf16* __restrict__ out) {
    const long i = ((long)blockIdx.x * 256 + threadIdx.x) * 8;
    float4 a = *(const float4*)(in + i);
    float4 b = *(const float4*)(in + i + 4);
    __align__(16) bf16 t[8];
    t[0] = __float2bfloat16(a.x); t[1] = __float2bfloat16(a.y);
    t[2] = __float2bfloat16(a.z); t[3] = __float2bfloat16(a.w);
    t[4] = __float2bfloat16(b.x); t[5] = __float2bfloat16(b.y);
    t[6] = __float2bfloat16(b.z); t[7] = __float2bfloat16(b.w);
    *(bf16x8*)(out + i) = *(const bf16x8*)t;
}

// ---------------- f32 [mat][R][Cn] -> bf16 [mat][Cn][R] transpose-convert ----------------
__global__ __launch_bounds__(256) void transpose_cvt_k(
    const float* __restrict__ in, bf16* __restrict__ out, int R, int Cn)
{
    __shared__ float t[32][33];
    const long mat = blockIdx.z;
    const float* inm = in + mat * (long)R * Cn;
    bf16* outm = out + mat * (long)R * Cn;
    const int c0 = blockIdx.x * 32, r0 = blockIdx.y * 32;
    const int tx = threadIdx.x & 31, ty = threadIdx.x >> 5;   // ty 0..7
#pragma unroll
    for (int i = 0; i < 4; ++i)
        t[ty + i*8][tx] = inm[(long)(r0 + ty + i*8) * Cn + c0 + tx];
    __syncthreads();
#pragma unroll
    for (int i = 0; i < 4; ++i)
        outm[(long)(c0 + ty + i*8) * R + r0 + tx] = __float2bfloat16(t[tx][ty + i*8]);
}

// ---------------- 128x128 tile GEMM: C = A[M,K] * Bt[N,K]^T + bias ----------------
template <bool C_F32>
__device__ __forceinline__ void gemm128x128(
    const bf16* __restrict__ A, int lda,
    const bf16* __restrict__ Bt, int ldb,
    void* __restrict__ C, int ldc,
    const float* __restrict__ bias,
    int Kdim, int m0, int n0)
{
    __shared__ __align__(16) bf16 As[128*32];
    __shared__ __align__(16) bf16 Bs[128*32];
    const int tid  = threadIdx.x;
    const int wave = tid >> 6, lane = tid & 63;
    const int lr = lane & 15, lq = lane >> 4;
    const int wrow = wave >> 1, wcol = wave & 1;
    const int sr = lane >> 2, sk = (lane & 3) * 8;

    const f32x4 zero4 = {0.f, 0.f, 0.f, 0.f};
    f32x4 acc[4][4];
#pragma unroll
    for (int i = 0; i < 4; ++i)
#pragma unroll
        for (int j = 0; j < 4; ++j) acc[i][j] = zero4;

    for (int k0 = 0; k0 < Kdim; k0 += 32) {
#pragma unroll
        for (int c = 0; c < 2; ++c) {
            const int r = wave*32 + c*16;   // 16 rows per (wave,c); lane scatter covers them
            async_cp16(A  + (long)(m0 + r + sr)*lda + k0 + sk, As + r*32);
            async_cp16(Bt + (long)(n0 + r + sr)*ldb + k0 + sk, Bs + r*32);
        }
        __syncthreads();   // drains vmcnt(0) before barrier
        bf16x8 af[4], bfr[4];
#pragma unroll
        for (int i = 0; i < 4; ++i)
            af[i] = *(const bf16x8*)(As + (wrow*64 + i*16 + lr)*32 + lq*8);
#pragma unroll
        for (int j = 0; j < 4; ++j)
            bfr[j] = *(const bf16x8*)(Bs + (wcol*64 + j*16 + lr)*32 + lq*8);
#pragma unroll
        for (int i = 0; i < 4; ++i)
#pragma unroll
            for (int j = 0; j < 4; ++j)
                acc[i][j] = __builtin_amdgcn_mfma_f32_16x16x32_bf16(af[i], bfr[j], acc[i][j], 0, 0, 0);
        __syncthreads();
    }
    // epilogue: C/D layout col=lane&15, row=(lane>>4)*4+reg (m89-verified)
#pragma unroll
    for (int j = 0; j < 4; ++j) {
        const int col = n0 + wcol*64 + j*16 + lr;
        const float bv = bias[col];
#pragma unroll
        for (int i = 0; i < 4; ++i) {
            const int row = m0 + wrow*64 + i*16 + lq*4;
#pragma unroll
            for (int r = 0; r < 4; ++r) {
                const float v = acc[i][j][r] + bv;
                if constexpr (C_F32) ((float*)C)[(long)(row + r)*ldc + col] = v;
                else ((bf16*)C)[(long)(row + r)*ldc + col] = __float2bfloat16(v);
            }
        }
    }
}

// ---------------- QKV projection ----------------
__global__ __launch_bounds__(256) void qkv_gemm_k(
    const bf16* __restrict__ X,
    const bf16* __restrict__ WTq, const bf16* __restrict__ WTk, const bf16* __restrict__ WTv,
    const float* __restrict__ bQ, const float* __restrict__ bK, const float* __restrict__ bV,
    bf16* __restrict__ Qo, bf16* __restrict__ Ko, bf16* __restrict__ Vo)
{
    const int mt  = blockIdx.x;        // 0..31
    const int sel = blockIdx.y >> 4;   // 0=Q 1=K 2=V
    const int h   = blockIdx.y & 15;
    const bf16* Bt; const float* bias; bf16* C;
    if (sel == 0)      { Bt = WTq; bias = bQ; C = Qo; }
    else if (sel == 1) { Bt = WTk; bias = bK; C = Ko; }
    else               { Bt = WTv; bias = bV; C = Vo; }
    gemm128x128<false>(X, D_MODEL, Bt + (long)h*DH*D_MODEL, D_MODEL,
                       C + h*DH, NH*DH, bias + h*DH, D_MODEL, mt*128, 0);
}

// ---------------- output projection (f32 out + f32 bias) ----------------
__global__ __launch_bounds__(256) void out_gemm_k(
    const bf16* __restrict__ Z, const bf16* __restrict__ WOT,
    const float* __restrict__ bO, float* __restrict__ Out)
{
    gemm128x128<true>(Z, D_MODEL, WOT, D_MODEL, Out, D_MODEL, bO, D_MODEL,
                      (int)blockIdx.x*128, (int)blockIdx.y*128);
}

// ---------------- flash attention (causal, online softmax) ----------------
__global__ __launch_bounds__(256) void flash_k(
    const bf16* __restrict__ Q, const bf16* __restrict__ K,
    const bf16* __restrict__ V, bf16* __restrict__ Z)
{
    __shared__ __align__(16) bf16 Qs[4*64*32];   // [ks][qrow][32feat]  16KB
    __shared__ __align__(16) bf16 Ks[4*64*32];   // [ks][key ][32feat]  16KB
    __shared__ __align__(16) bf16 Vt[128*72];    // [feat][key] pad 72  18KB
    __shared__ __align__(16) bf16 Ps[64*72];     // [qrow][key] pad 72   9KB

    const int qt = blockIdx.x;                 // q-tile (64 rows)
    const int b  = blockIdx.y >> 4, h = blockIdx.y & 15;
    const long base = (long)b*SEQ*D_MODEL + h*DH;
    const bf16* Qb = Q + base;
    const bf16* Kb = K + base;
    const bf16* Vb = V + base;
    bf16* Zb = Z + base;
    const int q0 = qt*64;
    const int tid = threadIdx.x, wave = tid >> 6, lane = tid & 63;
    const int lr = lane & 15, lq = lane >> 4;

    // stage Q once: Qs[ks=wave][row][32feat]; wave w stages feature slice w*32..
#pragma unroll
    for (int c = 0; c < 4; ++c)
        async_cp16(Qb + (long)(q0 + c*16 + (lane>>2))*D_MODEL + wave*32 + (lane&3)*8,
                   Qs + wave*2048 + c*512);

    const f32x4 zero4 = {0.f, 0.f, 0.f, 0.f};
    f32x4 o_acc[8];
#pragma unroll
    for (int jf = 0; jf < 8; ++jf) o_acc[jf] = zero4;
    float m_run[4], l_run[4];
#pragma unroll
    for (int r = 0; r < 4; ++r) { m_run[r] = -1e30f; l_run[r] = 0.f; }

    const float scale = 0.08838834764831845f;  // 1/sqrt(128)

    for (int kt = 0; kt <= qt; ++kt) {
        const int k0 = kt*64;
        __syncthreads();   // prev-tile consumers done; also drains Q staging (iter 0)
#pragma unroll
        for (int c = 0; c < 4; ++c)
            async_cp16(Kb + (long)(k0 + c*16 + (lane>>2))*D_MODEL + wave*32 + (lane&3)*8,
                       Ks + wave*2048 + c*512);
        // V tile transposed into LDS: Vt[feat][key]
#pragma unroll
        for (int p = 0; p < 4; ++p) {
            const int key = (tid & 15) + p*16;
            const int f0  = (tid >> 4) * 8;
            bf16x8 vv = *(const bf16x8*)(Vb + (long)(k0 + key)*D_MODEL + f0);
            const bf16* pv = (const bf16*)&vv;
#pragma unroll
            for (int j = 0; j < 8; ++j)
                Vt[(f0 + j)*72 + key] = pv[j];
        }
        __syncthreads();

        // S = Q K^T  (wave handles q-rows [wave*16, wave*16+16))
        bf16x8 aq[4];
#pragma unroll
        for (int ks = 0; ks < 4; ++ks)
            aq[ks] = *(const bf16x8*)(Qs + ks*2048 + (wave*16 + lr)*32 + lq*8);
        f32x4 sc[4];
#pragma unroll
        for (int jt = 0; jt < 4; ++jt) sc[jt] = zero4;
#pragma unroll
        for (int jt = 0; jt < 4; ++jt)
#pragma unroll
            for (int ks = 0; ks < 4; ++ks) {
                bf16x8 bk = *(const bf16x8*)(Ks + ks*2048 + (jt*16 + lr)*32 + lq*8);
                sc[jt] = __builtin_amdgcn_mfma_f32_16x16x32_bf16(aq[ks], bk, sc[jt], 0, 0, 0);
            }

        // scale + causal mask + row max (row=lq*4+r, col=lr per C-layout)
        float mx[4] = {-1e30f, -1e30f, -1e30f, -1e30f};
#pragma unroll
        for (int jt = 0; jt < 4; ++jt)
#pragma unroll
            for (int r = 0; r < 4; ++r) {
                const int qrow = q0 + wave*16 + lq*4 + r;
                const int kcol = k0 + jt*16 + lr;
                float v = sc[jt][r] * scale;
                if (kcol > qrow) v = -1e30f;
                sc[jt][r] = v;
                mx[r] = fmaxf(mx[r], v);
            }
#pragma unroll
        for (int off = 8; off >= 1; off >>= 1)
#pragma unroll
            for (int r = 0; r < 4; ++r)
                mx[r] = fmaxf(mx[r], __shfl_xor(mx[r], off, 64));

        // online softmax update
        float rs[4];
#pragma unroll
        for (int r = 0; r < 4; ++r) {
            const float mn = fmaxf(m_run[r], mx[r]);
            const float al = __expf(m_run[r] - mn);
            m_run[r] = mn;
            l_run[r] *= al;
            rs[r] = 0.f;
#pragma unroll
            for (int jt = 0; jt < 4; ++jt) {
                const float p = __expf(sc[jt][r] - mn);
                sc[jt][r] = p;
                rs[r] += p;
            }
#pragma unroll
            for (int jf = 0; jf < 8; ++jf) o_acc[jf][r] *= al;
        }
#pragma unroll
        for (int off = 8; off >= 1; off >>= 1)
#pragma unroll
            for (int r = 0; r < 4; ++r)
                rs[r] += __shfl_xor(rs[r], off, 64);
#pragma unroll
        for (int r = 0; r < 4; ++r) l_run[r] += rs[r];

        // P: C-layout regs -> LDS -> A-layout frags (wave-private rows, no barrier)
#pragma unroll
        for (int jt = 0; jt < 4; ++jt)
#pragma unroll
            for (int r = 0; r < 4; ++r)
                Ps[(wave*16 + lq*4 + r)*72 + jt*16 + lr] = __float2bfloat16(sc[jt][r]);

        bf16x8 pa0 = *(const bf16x8*)(Ps + (wave*16 + lr)*72 + lq*8);
        bf16x8 pa1 = *(const bf16x8*)(Ps + (wave*16 + lr)*72 + 32 + lq*8);
#pragma unroll
        for (int jf = 0; jf < 8; ++jf) {
            bf16x8 bv0 = *(const bf16x8*)(Vt + (jf*16 + lr)*72 + lq*8);
            bf16x8 bv1 = *(const bf16x8*)(Vt + (jf*16 + lr)*72 + 32 + lq*8);
            o_acc[jf] = __builtin_amdgcn_mfma_f32_16x16x32_bf16(pa0, bv0, o_acc[jf], 0, 0, 0);
            o_acc[jf] = __builtin_amdgcn_mfma_f32_16x16x32_bf16(pa1, bv1, o_acc[jf], 0, 0, 0);
        }
    }

    float inv[4];
#pragma unroll
    for (int r = 0; r < 4; ++r) inv[r] = 1.f / l_run[r];
#pragma unroll
    for (int jf = 0; jf < 8; ++jf)
#pragma unroll
        for (int r = 0; r < 4; ++r) {
            const int qrow = q0 + wave*16 + lq*4 + r;
            Zb[(long)qrow*D_MODEL + jf*16 + lr] = __float2bfloat16(o_acc[jf][r]*inv[r]);
        }
}

extern "C" void kernel_launch(void* const* d_in, const int* in_sizes, int n_in,
                              void* d_out, int out_size, void* d_ws, size_t ws_size,
                              hipStream_t stream) {
    const float* X  = (const float*)d_in[0];
    const float* WQ = (const float*)d_in[1];   // [NH][D_MODEL][DH] f32
    const float* WK = (const float*)d_in[2];
    const float* WV = (const float*)d_in[3];
    const float* WO = (const float*)d_in[4];   // [NH][DH][D_MODEL] == flat [2048][2048] f32
    const float* bQ = (const float*)d_in[5];   // [NH][DH] f32
    const float* bK = (const float*)d_in[6];
    const float* bV = (const float*)d_in[7];
    const float* bO = (const float*)d_in[8];   // [D_MODEL] f32
    float* out = (float*)d_out;

    bf16* ws = (bf16*)d_ws;
    const long WSZ = (long)NH*DH*D_MODEL;   // 4,194,304 elems (8 MiB bf16)
    const long MSZ = (long)MTOT*D_MODEL;    // 8,388,608 elems (16 MiB bf16)
    bf16* Xb  = ws;              // also reused as Zb after QKV GEMMs complete
    bf16* WTq = Xb + MSZ;
    bf16* WTk = WTq + WSZ;
    bf16* WTv = WTk + WSZ;
    bf16* WOT = WTv + WSZ;
    bf16* Qb  = WOT + WSZ;
    bf16* Kb  = Qb + MSZ;
    bf16* Vb  = Kb + MSZ;
    bf16* Zb  = Xb;              // alias: X consumed by QKV GEMM before flash writes Z
    // ws use: MSZ + 4*WSZ + 3*MSZ = 96 MiB

    cvt_k<<<MSZ/(256*8), 256, 0, stream>>>(X, Xb);
    transpose_cvt_k<<<dim3(DH/32, D_MODEL/32, NH), 256, 0, stream>>>(WQ, WTq, D_MODEL, DH);
    transpose_cvt_k<<<dim3(DH/32, D_MODEL/32, NH), 256, 0, stream>>>(WK, WTk, D_MODEL, DH);
    transpose_cvt_k<<<dim3(DH/32, D_MODEL/32, NH), 256, 0, stream>>>(WV, WTv, D_MODEL, DH);
    transpose_cvt_k<<<dim3(D_MODEL/32, D_MODEL/32, 1), 256, 0, stream>>>(WO, WOT, D_MODEL, D_MODEL);

    qkv_gemm_k<<<dim3(MTOT/128, 48), 256, 0, stream>>>(Xb, WTq, WTk, WTv, bQ, bK, bV, Qb, Kb, Vb);
    flash_k<<<dim3(SEQ/64, BATCH*NH), 256, 0, stream>>>(Qb, Kb, Vb, Zb);
    out_gemm_k<<<dim3(MTOT/128, D_MODEL/128), 256, 0, stream>>>(Zb, WOT, bO, out);
}

// Round 6
// 504.967 us; speedup vs baseline: 16.1304x; 1.0728x over previous
//
#include <hip/hip_runtime.h>
#include <hip/hip_bf16.h>

typedef __hip_bfloat16 bf16;
typedef __attribute__((ext_vector_type(8))) short bf16x8;  // 8 bf16 = 4 VGPRs (MFMA A/B frag)
typedef __attribute__((ext_vector_type(4))) float f32x4;   // MFMA C/D frag

#define D_MODEL 2048
#define SEQ     2048
#define NH      16
#define DH      128
#define BATCH   2
#define MTOT    (BATCH*SEQ)   // 4096

__device__ __forceinline__ void async_cp16(const bf16* g, bf16* l) {
    // wave-uniform LDS base; HW scatters lane i at base + i*16B
    __builtin_amdgcn_global_load_lds(
        (const __attribute__((address_space(1))) void*)g,
        (__attribute__((address_space(3))) void*)l, 16, 0, 0);
}

// ---------------- f32 -> bf16 elementwise convert (8 elems/thread) ----------------
__global__ __launch_bounds__(256) void cvt_k(const float* __restrict__ in,
                                             bf16* __restrict__ out) {
    const long i = ((long)blockIdx.x * 256 + threadIdx.x) * 8;
    float4 a = *(const float4*)(in + i);
    float4 b = *(const float4*)(in + i + 4);
    __align__(16) bf16 t[8];
    t[0] = __float2bfloat16(a.x); t[1] = __float2bfloat16(a.y);
    t[2] = __float2bfloat16(a.z); t[3] = __float2bfloat16(a.w);
    t[4] = __float2bfloat16(b.x); t[5] = __float2bfloat16(b.y);
    t[6] = __float2bfloat16(b.z); t[7] = __float2bfloat16(b.w);
    *(bf16x8*)(out + i) = *(const bf16x8*)t;
}

// ---- f32 [mat][R][Cn] -> bf16 [mat][Cn][R] transpose-convert; 3-src variant for QKV ----
__global__ __launch_bounds__(256) void transpose_cvt3_k(
    const float* __restrict__ in0, const float* __restrict__ in1,
    const float* __restrict__ in2,
    bf16* __restrict__ out, int R, int Cn, int mats_per_src)
{
    __shared__ float t[32][33];
    const int z = blockIdx.z;
    const int src = z / mats_per_src, mat = z % mats_per_src;
    const float* in = (src == 0) ? in0 : (src == 1) ? in1 : in2;
    const float* inm = in + (long)mat * R * Cn;
    bf16* outm = out + (long)z * R * Cn;
    const int c0 = blockIdx.x * 32, r0 = blockIdx.y * 32;
    const int tx = threadIdx.x & 31, ty = threadIdx.x >> 5;   // ty 0..7
#pragma unroll
    for (int i = 0; i < 4; ++i)
        t[ty + i*8][tx] = inm[(long)(r0 + ty + i*8) * Cn + c0 + tx];
    __syncthreads();
#pragma unroll
    for (int i = 0; i < 4; ++i)
        outm[(long)(c0 + ty + i*8) * R + r0 + tx] = __float2bfloat16(t[tx][ty + i*8]);
}

// ---------------- per-head V transpose: [b][key][h*DH+f] -> [(b,h)][f][key] bf16 ----------------
__global__ __launch_bounds__(256) void transpose_v_k(
    const bf16* __restrict__ V, bf16* __restrict__ VT)
{
    __shared__ bf16 t[32][33];
    const int bh = blockIdx.z;              // b*NH + h
    const int b = bh >> 4, h = bh & 15;
    const bf16* inm = V + (long)b*SEQ*D_MODEL + h*DH;       // [key][f] stride D_MODEL
    bf16* outm = VT + (long)bh*DH*SEQ;                      // [f][key] stride SEQ
    const int r0 = blockIdx.x * 32;         // key tile
    const int c0 = blockIdx.y * 32;         // feat tile
    const int tx = threadIdx.x & 31, ty = threadIdx.x >> 5;
#pragma unroll
    for (int i = 0; i < 4; ++i)
        t[ty + i*8][tx] = inm[(long)(r0 + ty + i*8)*D_MODEL + c0 + tx];
    __syncthreads();
#pragma unroll
    for (int i = 0; i < 4; ++i)
        outm[(long)(c0 + ty + i*8)*SEQ + r0 + tx] = t[tx][ty + i*8];
}

// ---------------- 128x128 tile GEMM: C = A[M,K] * Bt[N,K]^T + bias ----------------
template <bool C_F32>
__device__ __forceinline__ void gemm128x128(
    const bf16* __restrict__ A, int lda,
    const bf16* __restrict__ Bt, int ldb,
    void* __restrict__ C, int ldc,
    const float* __restrict__ bias,
    int Kdim, int m0, int n0)
{
    __shared__ __align__(16) bf16 As[128*32];
    __shared__ __align__(16) bf16 Bs[128*32];
    const int tid  = threadIdx.x;
    const int wave = tid >> 6, lane = tid & 63;
    const int lr = lane & 15, lq = lane >> 4;
    const int wrow = wave >> 1, wcol = wave & 1;
    const int sr = lane >> 2, sk = (lane & 3) * 8;

    const f32x4 zero4 = {0.f, 0.f, 0.f, 0.f};
    f32x4 acc[4][4];
#pragma unroll
    for (int i = 0; i < 4; ++i)
#pragma unroll
        for (int j = 0; j < 4; ++j) acc[i][j] = zero4;

    for (int k0 = 0; k0 < Kdim; k0 += 32) {
#pragma unroll
        for (int c = 0; c < 2; ++c) {
            const int r = wave*32 + c*16;
            async_cp16(A  + (long)(m0 + r + sr)*lda + k0 + sk, As + r*32);
            async_cp16(Bt + (long)(n0 + r + sr)*ldb + k0 + sk, Bs + r*32);
        }
        __syncthreads();
        bf16x8 af[4], bfr[4];
#pragma unroll
        for (int i = 0; i < 4; ++i)
            af[i] = *(const bf16x8*)(As + (wrow*64 + i*16 + lr)*32 + lq*8);
#pragma unroll
        for (int j = 0; j < 4; ++j)
            bfr[j] = *(const bf16x8*)(Bs + (wcol*64 + j*16 + lr)*32 + lq*8);
#pragma unroll
        for (int i = 0; i < 4; ++i)
#pragma unroll
            for (int j = 0; j < 4; ++j)
                acc[i][j] = __builtin_amdgcn_mfma_f32_16x16x32_bf16(af[i], bfr[j], acc[i][j], 0, 0, 0);
        __syncthreads();
    }
#pragma unroll
    for (int j = 0; j < 4; ++j) {
        const int col = n0 + wcol*64 + j*16 + lr;
        const float bv = bias[col];
#pragma unroll
        for (int i = 0; i < 4; ++i) {
            const int row = m0 + wrow*64 + i*16 + lq*4;
#pragma unroll
            for (int r = 0; r < 4; ++r) {
                const float v = acc[i][j][r] + bv;
                if constexpr (C_F32) ((float*)C)[(long)(row + r)*ldc + col] = v;
                else ((bf16*)C)[(long)(row + r)*ldc + col] = __float2bfloat16(v);
            }
        }
    }
}

// ---------------- QKV projection ----------------
__global__ __launch_bounds__(256) void qkv_gemm_k(
    const bf16* __restrict__ X, const bf16* __restrict__ WT3,
    const float* __restrict__ bQ, const float* __restrict__ bK, const float* __restrict__ bV,
    bf16* __restrict__ Qo, bf16* __restrict__ Ko, bf16* __restrict__ Vo)
{
    const int mt  = blockIdx.x;        // 0..31
    const int sel = blockIdx.y >> 4;   // 0=Q 1=K 2=V
    const int h   = blockIdx.y & 15;
    const float* bias; bf16* C;
    if (sel == 0)      { bias = bQ; C = Qo; }
    else if (sel == 1) { bias = bK; C = Ko; }
    else               { bias = bV; C = Vo; }
    gemm128x128<false>(X, D_MODEL, WT3 + (long)blockIdx.y*DH*D_MODEL, D_MODEL,
                       C + h*DH, NH*DH, bias + h*DH, D_MODEL, mt*128, 0);
}

// ---------------- output projection (f32 out + f32 bias) ----------------
__global__ __launch_bounds__(256) void out_gemm_k(
    const bf16* __restrict__ Z, const bf16* __restrict__ WOT,
    const float* __restrict__ bO, float* __restrict__ Out)
{
    gemm128x128<true>(Z, D_MODEL, WOT, D_MODEL, Out, D_MODEL, bO, D_MODEL,
                      (int)blockIdx.x*128, (int)blockIdx.y*128);
}

// ---------------- flash attention (causal, online softmax) ----------------
__global__ __launch_bounds__(256) void flash_k(
    const bf16* __restrict__ Q, const bf16* __restrict__ K,
    const bf16* __restrict__ VT, bf16* __restrict__ Z)
{
    __shared__ __align__(16) bf16 Ks[4*64*32];   // [ks][key][32feat]   16KB
    __shared__ __align__(16) bf16 Vts[2*128*32]; // [ks2][feat][32key]  16KB
    __shared__ __align__(16) bf16 Ps[64*72];     // [qrow][key] pad 72   9KB

    const int qt = (int)(gridDim.x - 1) - (int)blockIdx.x;   // big tiles dispatch first
    const int bh = blockIdx.y;
    const int b  = bh >> 4, h = bh & 15;
    const long base = (long)b*SEQ*D_MODEL + h*DH;
    const bf16* Qb  = Q + base;
    const bf16* Kb  = K + base;
    const bf16* VTb = VT + (long)bh*DH*SEQ;      // [feat][key] stride SEQ
    bf16* Zb = Z + base;
    const int q0 = qt*64;
    const int tid = threadIdx.x, wave = tid >> 6, lane = tid & 63;
    const int lr = lane & 15, lq = lane >> 4;

    // Q A-frags in registers: wave owns q-rows wave*16..+16; aq[ks] covers feats ks*32..+32
    bf16x8 aq[4];
#pragma unroll
    for (int ks = 0; ks < 4; ++ks)
        aq[ks] = *(const bf16x8*)(Qb + (long)(q0 + wave*16 + lr)*D_MODEL + ks*32 + lq*8);

    const f32x4 zero4 = {0.f, 0.f, 0.f, 0.f};
    f32x4 o_acc[8];
#pragma unroll
    for (int jf = 0; jf < 8; ++jf) o_acc[jf] = zero4;
    float m_run[4], l_run[4];
#pragma unroll
    for (int r = 0; r < 4; ++r) { m_run[r] = -1e30f; l_run[r] = 0.f; }

    const float scale = 0.08838834764831845f;  // 1/sqrt(128)

    for (int kt = 0; kt <= qt; ++kt) {
        const int k0 = kt*64;
        __syncthreads();   // all waves done reading Ks/Vts of prev tile
        // K tile: Ks[ks=wave][key][32feat]
#pragma unroll
        for (int c = 0; c < 4; ++c)
            async_cp16(Kb + (long)(k0 + c*16 + (lane>>2))*D_MODEL + wave*32 + (lane&3)*8,
                       Ks + wave*2048 + c*512);
        // V^T tile: Vts[ks2][feat][32key]; wave stages feats wave*32..+32
#pragma unroll
        for (int ks2 = 0; ks2 < 2; ++ks2)
#pragma unroll
            for (int i = 0; i < 2; ++i)
                async_cp16(VTb + (long)(wave*32 + i*16 + (lane>>2))*SEQ + k0 + ks2*32 + (lane&3)*8,
                           Vts + ks2*4096 + (wave*32 + i*16)*32);
        __syncthreads();

        // S = Q K^T  (wave handles q-rows [wave*16, wave*16+16))
        f32x4 sc[4];
#pragma unroll
        for (int jt = 0; jt < 4; ++jt) sc[jt] = zero4;
#pragma unroll
        for (int jt = 0; jt < 4; ++jt)
#pragma unroll
            for (int ks = 0; ks < 4; ++ks) {
                bf16x8 bk = *(const bf16x8*)(Ks + ks*2048 + (jt*16 + lr)*32 + lq*8);
                sc[jt] = __builtin_amdgcn_mfma_f32_16x16x32_bf16(aq[ks], bk, sc[jt], 0, 0, 0);
            }

        // scale + causal mask + row max (row=lq*4+r, col=lr per C-layout)
        float mx[4] = {-1e30f, -1e30f, -1e30f, -1e30f};
#pragma unroll
        for (int jt = 0; jt < 4; ++jt)
#pragma unroll
            for (int r = 0; r < 4; ++r) {
                const int qrow = q0 + wave*16 + lq*4 + r;
                const int kcol = k0 + jt*16 + lr;
                float v = sc[jt][r] * scale;
                if (kcol > qrow) v = -1e30f;
                sc[jt][r] = v;
                mx[r] = fmaxf(mx[r], v);
            }
#pragma unroll
        for (int off = 8; off >= 1; off >>= 1)
#pragma unroll
            for (int r = 0; r < 4; ++r)
                mx[r] = fmaxf(mx[r], __shfl_xor(mx[r], off, 64));

        // online softmax update
        float rs[4];
#pragma unroll
        for (int r = 0; r < 4; ++r) {
            const float mn = fmaxf(m_run[r], mx[r]);
            const float al = __expf(m_run[r] - mn);
            m_run[r] = mn;
            l_run[r] *= al;
            rs[r] = 0.f;
#pragma unroll
            for (int jt = 0; jt < 4; ++jt) {
                const float p = __expf(sc[jt][r] - mn);
                sc[jt][r] = p;
                rs[r] += p;
            }
#pragma unroll
            for (int jf = 0; jf < 8; ++jf) o_acc[jf][r] *= al;
        }
#pragma unroll
        for (int off = 8; off >= 1; off >>= 1)
#pragma unroll
            for (int r = 0; r < 4; ++r)
                rs[r] += __shfl_xor(rs[r], off, 64);
#pragma unroll
        for (int r = 0; r < 4; ++r) l_run[r] += rs[r];

        // P: C-layout regs -> LDS -> A-layout frags (wave-private rows)
#pragma unroll
        for (int jt = 0; jt < 4; ++jt)
#pragma unroll
            for (int r = 0; r < 4; ++r)
                Ps[(wave*16 + lq*4 + r)*72 + jt*16 + lr] = __float2bfloat16(sc[jt][r]);

        bf16x8 pa0 = *(const bf16x8*)(Ps + (wave*16 + lr)*72 + lq*8);
        bf16x8 pa1 = *(const bf16x8*)(Ps + (wave*16 + lr)*72 + 32 + lq*8);
#pragma unroll
        for (int jf = 0; jf < 8; ++jf) {
            bf16x8 bv0 = *(const bf16x8*)(Vts + (jf*16 + lr)*32 + lq*8);
            bf16x8 bv1 = *(const bf16x8*)(Vts + 4096 + (jf*16 + lr)*32 + lq*8);
            o_acc[jf] = __builtin_amdgcn_mfma_f32_16x16x32_bf16(pa0, bv0, o_acc[jf], 0, 0, 0);
            o_acc[jf] = __builtin_amdgcn_mfma_f32_16x16x32_bf16(pa1, bv1, o_acc[jf], 0, 0, 0);
        }
    }

    float inv[4];
#pragma unroll
    for (int r = 0; r < 4; ++r) inv[r] = 1.f / l_run[r];
#pragma unroll
    for (int jf = 0; jf < 8; ++jf)
#pragma unroll
        for (int r = 0; r < 4; ++r) {
            const int qrow = q0 + wave*16 + lq*4 + r;
            Zb[(long)qrow*D_MODEL + jf*16 + lr] = __float2bfloat16(o_acc[jf][r]*inv[r]);
        }
}

extern "C" void kernel_launch(void* const* d_in, const int* in_sizes, int n_in,
                              void* d_out, int out_size, void* d_ws, size_t ws_size,
                              hipStream_t stream) {
    const float* X  = (const float*)d_in[0];
    const float* WQ = (const float*)d_in[1];   // [NH][D_MODEL][DH] f32
    const float* WK = (const float*)d_in[2];
    const float* WV = (const float*)d_in[3];
    const float* WO = (const float*)d_in[4];   // flat [2048][2048] f32
    const float* bQ = (const float*)d_in[5];
    const float* bK = (const float*)d_in[6];
    const float* bV = (const float*)d_in[7];
    const float* bO = (const float*)d_in[8];
    float* out = (float*)d_out;

    bf16* ws = (bf16*)d_ws;
    const long WSZ = (long)NH*DH*D_MODEL;   // 4,194,304 elems (8 MiB bf16)
    const long MSZ = (long)MTOT*D_MODEL;    // 8,388,608 elems (16 MiB bf16)
    bf16* Xb  = ws;
    bf16* WT3 = Xb + MSZ;        // QKV transposed weights, 48 mats of [DH? no: [3*NH][DH? ] 3*WSZ
    bf16* WOT = WT3 + 3*WSZ;
    bf16* Qb  = WOT + WSZ;
    bf16* Kb  = Qb + MSZ;
    bf16* Vb  = Kb + MSZ;
    bf16* Zb  = Xb;              // alias: X dead after QKV GEMM
    bf16* VT  = WT3;             // alias: QKV weight transposes dead after QKV GEMM (16 MiB fits in 24)
    // ws use: MSZ + 4*WSZ + 3*MSZ = 96 MiB

    cvt_k<<<MSZ/(256*8), 256, 0, stream>>>(X, Xb);
    transpose_cvt3_k<<<dim3(DH/32, D_MODEL/32, 3*NH), 256, 0, stream>>>(
        WQ, WK, WV, WT3, D_MODEL, DH, NH);
    transpose_cvt3_k<<<dim3(D_MODEL/32, D_MODEL/32, 1), 256, 0, stream>>>(
        WO, WO, WO, WOT, D_MODEL, D_MODEL, 1);

    qkv_gemm_k<<<dim3(MTOT/128, 48), 256, 0, stream>>>(Xb, WT3, bQ, bK, bV, Qb, Kb, Vb);
    transpose_v_k<<<dim3(SEQ/32, DH/32, BATCH*NH), 256, 0, stream>>>(Vb, VT);
    flash_k<<<dim3(SEQ/64, BATCH*NH), 256, 0, stream>>>(Qb, Kb, VT, Zb);
    out_gemm_k<<<dim3(MTOT/128, D_MODEL/128), 256, 0, stream>>>(Zb, WOT, bO, out);
}

// Round 8
// 459.511 us; speedup vs baseline: 17.7260x; 1.0989x over previous
//
#include <hip/hip_runtime.h>
#include <hip/hip_bf16.h>

typedef __hip_bfloat16 bf16;
typedef __attribute__((ext_vector_type(8))) short bf16x8;  // 8 bf16 = 4 VGPRs (MFMA A/B frag)
typedef __attribute__((ext_vector_type(4))) short bf16x4;  // 4 bf16 = 8B packed store
typedef __attribute__((ext_vector_type(4))) float f32x4;   // MFMA C/D frag

#define D_MODEL 2048
#define SEQ     2048
#define NH      16
#define DH      128
#define BATCH   2
#define MTOT    (BATCH*SEQ)   // 4096

__device__ __forceinline__ void async_cp16(const bf16* g, bf16* l) {
    // wave-uniform LDS base; HW scatters lane i at base + i*16B
    __builtin_amdgcn_global_load_lds(
        (const __attribute__((address_space(1))) void*)g,
        (__attribute__((address_space(3))) void*)l, 16, 0, 0);
}

__device__ __forceinline__ short bf16bits(float f) {
    bf16 b = __float2bfloat16(f);
    return *reinterpret_cast<short*>(&b);
}

// ---------------- f32 -> bf16 elementwise convert (8 elems/thread) ----------------
__global__ __launch_bounds__(256) void cvt_k(const float* __restrict__ in,
                                             bf16* __restrict__ out) {
    const long i = ((long)blockIdx.x * 256 + threadIdx.x) * 8;
    float4 a = *(const float4*)(in + i);
    float4 b = *(const float4*)(in + i + 4);
    __align__(16) bf16 t[8];
    t[0] = __float2bfloat16(a.x); t[1] = __float2bfloat16(a.y);
    t[2] = __float2bfloat16(a.z); t[3] = __float2bfloat16(a.w);
    t[4] = __float2bfloat16(b.x); t[5] = __float2bfloat16(b.y);
    t[6] = __float2bfloat16(b.z); t[7] = __float2bfloat16(b.w);
    *(bf16x8*)(out + i) = *(const bf16x8*)t;
}

// ---- f32 [mat][R][Cn] -> bf16 [mat][Cn][R] transpose-convert; 3-src variant for QKV ----
__global__ __launch_bounds__(256) void transpose_cvt3_k(
    const float* __restrict__ in0, const float* __restrict__ in1,
    const float* __restrict__ in2,
    bf16* __restrict__ out, int R, int Cn, int mats_per_src)
{
    __shared__ float t[32][33];
    const int z = blockIdx.z;
    const int src = z / mats_per_src, mat = z % mats_per_src;
    const float* in = (src == 0) ? in0 : (src == 1) ? in1 : in2;
    const float* inm = in + (long)mat * R * Cn;
    bf16* outm = out + (long)z * R * Cn;
    const int c0 = blockIdx.x * 32, r0 = blockIdx.y * 32;
    const int tx = threadIdx.x & 31, ty = threadIdx.x >> 5;   // ty 0..7
#pragma unroll
    for (int i = 0; i < 4; ++i)
        t[ty + i*8][tx] = inm[(long)(r0 + ty + i*8) * Cn + c0 + tx];
    __syncthreads();
#pragma unroll
    for (int i = 0; i < 4; ++i)
        outm[(long)(c0 + ty + i*8) * R + r0 + tx] = __float2bfloat16(t[tx][ty + i*8]);
}

// ---------------- per-head V transpose: [b][key][h*DH+f] -> [(b,h)][f][key] bf16 ----------------
__global__ __launch_bounds__(256) void transpose_v_k(
    const bf16* __restrict__ V, bf16* __restrict__ VT)
{
    __shared__ bf16 t[32][33];
    const int bh = blockIdx.z;              // b*NH + h
    const int b = bh >> 4, h = bh & 15;
    const bf16* inm = V + (long)b*SEQ*D_MODEL + h*DH;       // [key][f] stride D_MODEL
    bf16* outm = VT + (long)bh*DH*SEQ;                      // [f][key] stride SEQ
    const int r0 = blockIdx.x * 32;         // key tile
    const int c0 = blockIdx.y * 32;         // feat tile
    const int tx = threadIdx.x & 31, ty = threadIdx.x >> 5;
#pragma unroll
    for (int i = 0; i < 4; ++i)
        t[ty + i*8][tx] = inm[(long)(r0 + ty + i*8)*D_MODEL + c0 + tx];
    __syncthreads();
#pragma unroll
    for (int i = 0; i < 4; ++i)
        outm[(long)(c0 + ty + i*8)*SEQ + r0 + tx] = t[tx][ty + i*8];
}

// ---------------- 128x128 tile GEMM: C = A[M,K] * Bt[N,K]^T + bias ----------------
template <bool C_F32>
__device__ __forceinline__ void gemm128x128(
    const bf16* __restrict__ A, int lda,
    const bf16* __restrict__ Bt, int ldb,
    void* __restrict__ C, int ldc,
    const float* __restrict__ bias,
    int Kdim, int m0, int n0)
{
    __shared__ __align__(16) bf16 As[128*32];
    __shared__ __align__(16) bf16 Bs[128*32];
    const int tid  = threadIdx.x;
    const int wave = tid >> 6, lane = tid & 63;
    const int lr = lane & 15, lq = lane >> 4;
    const int wrow = wave >> 1, wcol = wave & 1;
    const int sr = lane >> 2, sk = (lane & 3) * 8;

    const f32x4 zero4 = {0.f, 0.f, 0.f, 0.f};
    f32x4 acc[4][4];
#pragma unroll
    for (int i = 0; i < 4; ++i)
#pragma unroll
        for (int j = 0; j < 4; ++j) acc[i][j] = zero4;

    for (int k0 = 0; k0 < Kdim; k0 += 32) {
#pragma unroll
        for (int c = 0; c < 2; ++c) {
            const int r = wave*32 + c*16;
            async_cp16(A  + (long)(m0 + r + sr)*lda + k0 + sk, As + r*32);
            async_cp16(Bt + (long)(n0 + r + sr)*ldb + k0 + sk, Bs + r*32);
        }
        __syncthreads();
        bf16x8 af[4], bfr[4];
#pragma unroll
        for (int i = 0; i < 4; ++i)
            af[i] = *(const bf16x8*)(As + (wrow*64 + i*16 + lr)*32 + lq*8);
#pragma unroll
        for (int j = 0; j < 4; ++j)
            bfr[j] = *(const bf16x8*)(Bs + (wcol*64 + j*16 + lr)*32 + lq*8);
#pragma unroll
        for (int i = 0; i < 4; ++i)
#pragma unroll
            for (int j = 0; j < 4; ++j)
                acc[i][j] = __builtin_amdgcn_mfma_f32_16x16x32_bf16(af[i], bfr[j], acc[i][j], 0, 0, 0);
        __syncthreads();
    }
#pragma unroll
    for (int j = 0; j < 4; ++j) {
        const int col = n0 + wcol*64 + j*16 + lr;
        const float bv = bias[col];
#pragma unroll
        for (int i = 0; i < 4; ++i) {
            const int row = m0 + wrow*64 + i*16 + lq*4;
#pragma unroll
            for (int r = 0; r < 4; ++r) {
                const float v = acc[i][j][r] + bv;
                if constexpr (C_F32) ((float*)C)[(long)(row + r)*ldc + col] = v;
                else ((bf16*)C)[(long)(row + r)*ldc + col] = __float2bfloat16(v);
            }
        }
    }
}

// ---------------- QKV projection ----------------
__global__ __launch_bounds__(256) void qkv_gemm_k(
    const bf16* __restrict__ X, const bf16* __restrict__ WT3,
    const float* __restrict__ bQ, const float* __restrict__ bK, const float* __restrict__ bV,
    bf16* __restrict__ Qo, bf16* __restrict__ Ko, bf16* __restrict__ Vo)
{
    const int mt  = blockIdx.x;        // 0..31
    const int sel = blockIdx.y >> 4;   // 0=Q 1=K 2=V
    const int h   = blockIdx.y & 15;
    const float* bias; bf16* C;
    if (sel == 0)      { bias = bQ; C = Qo; }
    else if (sel == 1) { bias = bK; C = Ko; }
    else               { bias = bV; C = Vo; }
    gemm128x128<false>(X, D_MODEL, WT3 + (long)blockIdx.y*DH*D_MODEL, D_MODEL,
                       C + h*DH, NH*DH, bias + h*DH, D_MODEL, mt*128, 0);
}

// ---------------- output projection (f32 out + f32 bias) ----------------
__global__ __launch_bounds__(256) void out_gemm_k(
    const bf16* __restrict__ Z, const bf16* __restrict__ WOT,
    const float* __restrict__ bO, float* __restrict__ Out)
{
    gemm128x128<true>(Z, D_MODEL, WOT, D_MODEL, Out, D_MODEL, bO, D_MODEL,
                      (int)blockIdx.x*128, (int)blockIdx.y*128);
}

// ---------------- flash attention: S^T = K Q^T, O^T = V^T P^T ----------------
// P^T moves C-frag -> B-frag via LDS Ps[qrow][key] (wave-private rows; the
// ds_bpermute route is NOT usable: wave64 bpermute can't cross 32-lane halves).
__global__ __launch_bounds__(256) void flash_k(
    const bf16* __restrict__ Q, const bf16* __restrict__ K,
    const bf16* __restrict__ VT, bf16* __restrict__ Z)
{
    __shared__ __align__(16) bf16 Ks[4*64*32];   // [ks][key][32feat]   16KB
    __shared__ __align__(16) bf16 Vts[2*128*32]; // [kf][feat][32key]   16KB
    __shared__ __align__(16) bf16 Ps[64*72];     // [qrow][key] pad 72   9KB

    const int qt = (int)(gridDim.x - 1) - (int)blockIdx.x;   // big tiles dispatch first
    const int bh = blockIdx.y;
    const int b  = bh >> 4, h = bh & 15;
    const long base = (long)b*SEQ*D_MODEL + h*DH;
    const bf16* Qb  = Q + base;
    const bf16* Kb  = K + base;
    const bf16* VTb = VT + (long)bh*DH*SEQ;      // [feat][key] stride SEQ
    bf16* Zb = Z + base;
    const int q0 = qt*64;
    const int tid = threadIdx.x, wave = tid >> 6, lane = tid & 63;
    const int lr = lane & 15, lq = lane >> 4;

    // Q B-frags in registers: lane holds q-row (q0+wave*16+lr), feats ks*32+lq*8..+8
    bf16x8 aq[4];
#pragma unroll
    for (int ks = 0; ks < 4; ++ks)
        aq[ks] = *(const bf16x8*)(Qb + (long)(q0 + wave*16 + lr)*D_MODEL + ks*32 + lq*8);

    const f32x4 zero4 = {0.f, 0.f, 0.f, 0.f};
    f32x4 o_acc[8];           // O^T: col=qrow(lr), row=feat(jf*16+lq*4+r)
#pragma unroll
    for (int jf = 0; jf < 8; ++jf) o_acc[jf] = zero4;
    float m_run = -1e30f, l_run = 0.f;   // per-lane (qrow=lr), scaled domain

    const float scale = 0.08838834764831845f;  // 1/sqrt(128)

    for (int kt = 0; kt <= qt; ++kt) {
        const int k0 = kt*64;
        __syncthreads();   // all waves done reading Ks/Vts of prev tile
#pragma unroll
        for (int c = 0; c < 4; ++c)
            async_cp16(Kb + (long)(k0 + c*16 + (lane>>2))*D_MODEL + wave*32 + (lane&3)*8,
                       Ks + wave*2048 + c*512);
#pragma unroll
        for (int kf = 0; kf < 2; ++kf)
#pragma unroll
            for (int i = 0; i < 2; ++i)
                async_cp16(VTb + (long)(wave*32 + i*16 + (lane>>2))*SEQ + k0 + kf*32 + (lane&3)*8,
                           Vts + kf*4096 + (wave*32 + i*16)*32);
        __syncthreads();

        // S^T = K Q^T: sc[mt] C-frag: col=qrow(lr), row=key(mt*16+lq*4+r)
        f32x4 sc[4];
#pragma unroll
        for (int mt = 0; mt < 4; ++mt) sc[mt] = zero4;
#pragma unroll
        for (int mt = 0; mt < 4; ++mt)
#pragma unroll
            for (int ks = 0; ks < 4; ++ks) {
                bf16x8 bk = *(const bf16x8*)(Ks + ks*2048 + (mt*16 + lr)*32 + lq*8);
                sc[mt] = __builtin_amdgcn_mfma_f32_16x16x32_bf16(bk, aq[ks], sc[mt], 0, 0, 0);
            }

        // causal mask: only the diagonal tile is partial
        if (kt == qt) {
            const int qrl = wave*16 + lr;   // lane's q-row within the 64-tile (q0==k0)
#pragma unroll
            for (int mt = 0; mt < 4; ++mt)
#pragma unroll
                for (int r = 0; r < 4; ++r)
                    if (mt*16 + lq*4 + r > qrl) sc[mt][r] = -1e30f;
        }

        // row max over lane's 16 keys, then across lq groups (xor 16,32)
        float mx = sc[0][0];
#pragma unroll
        for (int mt = 0; mt < 4; ++mt)
#pragma unroll
            for (int r = 0; r < 4; ++r) mx = fmaxf(mx, sc[mt][r]);
        mx = fmaxf(mx, __shfl_xor(mx, 16, 64));
        mx = fmaxf(mx, __shfl_xor(mx, 32, 64));
        mx *= scale;   // scaled domain

        const float mn = fmaxf(m_run, mx);
        const float al = __expf(m_run - mn);
        float rs = 0.f;
#pragma unroll
        for (int mt = 0; mt < 4; ++mt)
#pragma unroll
            for (int r = 0; r < 4; ++r) {
                const float p = __expf(fmaf(sc[mt][r], scale, -mn));
                sc[mt][r] = p;
                rs += p;
            }
        rs += __shfl_xor(rs, 16, 64);
        rs += __shfl_xor(rs, 32, 64);
        l_run = l_run * al + rs;
        m_run = mn;
#pragma unroll
        for (int jf = 0; jf < 8; ++jf)
#pragma unroll
            for (int r = 0; r < 4; ++r) o_acc[jf][r] *= al;

        // P^T: C-frag (qrow=lr, key=mt*16+lq*4+r) -> Ps[qrow][key] -> contiguous B-frag
        // rows are wave-private (qrow = wave*16+lr); same-wave write->read, no barrier
#pragma unroll
        for (int mt = 0; mt < 4; ++mt)
#pragma unroll
            for (int r = 0; r < 4; ++r)
                Ps[(wave*16 + lr)*72 + mt*16 + lq*4 + r] = __float2bfloat16(sc[mt][r]);

        bf16x8 pb0 = *(const bf16x8*)(Ps + (wave*16 + lr)*72 + lq*8);
        bf16x8 pb1 = *(const bf16x8*)(Ps + (wave*16 + lr)*72 + 32 + lq*8);

        // O^T += V^T P^T
#pragma unroll
        for (int jf = 0; jf < 8; ++jf) {
            bf16x8 av0 = *(const bf16x8*)(Vts + (jf*16 + lr)*32 + lq*8);
            bf16x8 av1 = *(const bf16x8*)(Vts + 4096 + (jf*16 + lr)*32 + lq*8);
            o_acc[jf] = __builtin_amdgcn_mfma_f32_16x16x32_bf16(av0, pb0, o_acc[jf], 0, 0, 0);
            o_acc[jf] = __builtin_amdgcn_mfma_f32_16x16x32_bf16(av1, pb1, o_acc[jf], 0, 0, 0);
        }
    }

    const float inv = 1.f / l_run;
    const long zrow = (long)(q0 + wave*16 + lr) * D_MODEL;
#pragma unroll
    for (int jf = 0; jf < 8; ++jf) {
        bf16x4 pk;
#pragma unroll
        for (int r = 0; r < 4; ++r) pk[r] = bf16bits(o_acc[jf][r] * inv);
        *(bf16x4*)(Zb + zrow + jf*16 + lq*4) = pk;
    }
}

extern "C" void kernel_launch(void* const* d_in, const int* in_sizes, int n_in,
                              void* d_out, int out_size, void* d_ws, size_t ws_size,
                              hipStream_t stream) {
    const float* X  = (const float*)d_in[0];
    const float* WQ = (const float*)d_in[1];   // [NH][D_MODEL][DH] f32
    const float* WK = (const float*)d_in[2];
    const float* WV = (const float*)d_in[3];
    const float* WO = (const float*)d_in[4];   // flat [2048][2048] f32
    const float* bQ = (const float*)d_in[5];
    const float* bK = (const float*)d_in[6];
    const float* bV = (const float*)d_in[7];
    const float* bO = (const float*)d_in[8];
    float* out = (float*)d_out;

    bf16* ws = (bf16*)d_ws;
    const long WSZ = (long)NH*DH*D_MODEL;   // 4,194,304 elems (8 MiB bf16)
    const long MSZ = (long)MTOT*D_MODEL;    // 8,388,608 elems (16 MiB bf16)
    bf16* Xb  = ws;
    bf16* WT3 = Xb + MSZ;        // 3*WSZ: transposed QKV weights [48][DH][D_MODEL]
    bf16* WOT = WT3 + 3*WSZ;
    bf16* Qb  = WOT + WSZ;
    bf16* Kb  = Qb + MSZ;
    bf16* Vb  = Kb + MSZ;
    bf16* Zb  = Xb;              // alias: X dead after QKV GEMM
    bf16* VT  = WT3;             // alias: QKV weight transposes dead after QKV GEMM
    // ws use: MSZ + 4*WSZ + 3*MSZ = 96 MiB

    cvt_k<<<MSZ/(256*8), 256, 0, stream>>>(X, Xb);
    transpose_cvt3_k<<<dim3(DH/32, D_MODEL/32, 3*NH), 256, 0, stream>>>(
        WQ, WK, WV, WT3, D_MODEL, DH, NH);
    transpose_cvt3_k<<<dim3(D_MODEL/32, D_MODEL/32, 1), 256, 0, stream>>>(
        WO, WO, WO, WOT, D_MODEL, D_MODEL, 1);

    qkv_gemm_k<<<dim3(MTOT/128, 48), 256, 0, stream>>>(Xb, WT3, bQ, bK, bV, Qb, Kb, Vb);
    transpose_v_k<<<dim3(SEQ/32, DH/32, BATCH*NH), 256, 0, stream>>>(Vb, VT);
    flash_k<<<dim3(SEQ/64, BATCH*NH), 256, 0, stream>>>(Qb, Kb, VT, Zb);
    out_gemm_k<<<dim3(MTOT/128, D_MODEL/128), 256, 0, stream>>>(Zb, WOT, bO, out);
}